// Round 10
// baseline (1305.711 us; speedup 1.0000x reference)
//
#include <hip/hip_runtime.h>

// ODENet: y_{t+1} = y_t + f(x_t, y_t),  f = W3^T tanh(W2^T tanh(x*W1[0] + y*W1[1] + b1) + b2) + b3
// out[t][b] = y_t (pre-update state).  SEQ=2048 sequential steps, BATCH=512 independent chains.
//
// Round-10: R9 with the burst-store off-by-one FIXED. At iteration i the fold applies
// f(step tb+i-1), so after the update y holds Y_{tb+i} (the state ENTERING step tb+i) —
// store it directly at slot tb+i. (R9 shifted by one: out[t]=Y_{t-1}, absmax=|f|~0.021.)
//  - y history in registers, ONE burst store per 8-step block (one vmcnt drain per block,
//    wave 0 only, instead of a drain at every barrier).
//  - exp2-form tanh (exact; no clamp): tanh(x) = 1 - 2/(exp2(2*log2e*x)+1).
//  - DPP reduce split: r01 = row16(s01) hides under tiles-2,3 MFMA; tail = row16(s23)+r01.
//  - b3 pre-folded into base (off-path); fold->pre critical path = 3 adds + fma + tanh.
//  - R8 base: 256 WGs x 256 thr, M=2 chains at MFMA rows 0,4; 1 wave/SIMD; padded A_lds
//    (row stride 288 ushorts -> disjoint bank halves); fold-at-top with -b3/4 partial init.

#define SEQ 2048
#define BATCH 512
#define HID 256
#define LDA 288  // padded row stride (ushorts); rows land on disjoint bank halves

typedef __bf16 bf16x8 __attribute__((ext_vector_type(8)));
typedef short short8 __attribute__((ext_vector_type(8)));
typedef float f32x4 __attribute__((ext_vector_type(4)));

__device__ __forceinline__ unsigned short f2bf_rne(float f) {
  unsigned u = __builtin_bit_cast(unsigned, f);
  u += 0x7fffu + ((u >> 16) & 1u);
  return (unsigned short)(u >> 16);
}

// Exact tanh via exp2: tanh(x) = 1 - 2/(exp2(2*log2e*x) + 1).
// x->+inf: exp2=inf, rcp=0 -> 1.  x->-inf: exp2=0 -> 1-2 = -1.  No clamp needed.
__device__ __forceinline__ float tanh_e(float x) {
  float t = __builtin_amdgcn_exp2f(x * 2.8853900817779268f);
  return __builtin_fmaf(-2.f, __builtin_amdgcn_rcpf(t + 1.f), 1.f);
}

// Sum over each 16-lane DPP row; valid in lane 15 of the row.
__device__ __forceinline__ float row16_sum_to_lane15(float v) {
  int s;
  s = __builtin_amdgcn_update_dpp(0, __builtin_bit_cast(int, v), 0x111, 0xf, 0xf, true);
  v += __builtin_bit_cast(float, s);
  s = __builtin_amdgcn_update_dpp(0, __builtin_bit_cast(int, v), 0x112, 0xf, 0xf, true);
  v += __builtin_bit_cast(float, s);
  s = __builtin_amdgcn_update_dpp(0, __builtin_bit_cast(int, v), 0x114, 0xf, 0xf, true);
  v += __builtin_bit_cast(float, s);
  s = __builtin_amdgcn_update_dpp(0, __builtin_bit_cast(int, v), 0x118, 0xf, 0xf, true);
  v += __builtin_bit_cast(float, s);
  return v;
}

// Pack W2 (256x256 fp32, row-major [k][c]) into bf16 B-fragments.
// ws[(((tile*8)+kc)*64 + lane)*8 + e] = bf16(W2[k][c]) with
//   k = kc*32 + (lane>>4)*8 + e,  c = tile*16 + (lane&15)
__global__ void pack_w2_kernel(const float* __restrict__ W2,
                               unsigned short* __restrict__ ws) {
  int idx = blockIdx.x * 256 + threadIdx.x;     // 0..65535
  int e    = idx & 7;
  int l    = (idx >> 3) & 63;
  int kc   = (idx >> 9) & 7;
  int tile = idx >> 12;                         // 0..15
  int k = kc * 32 + (l >> 4) * 8 + e;
  int c = tile * 16 + (l & 15);
  ws[idx] = f2bf_rne(W2[k * HID + c]);
}

__global__ __launch_bounds__(256, 1) void odenet_kernel(
    const float* __restrict__ x, const float* __restrict__ W1,
    const float* __restrict__ b1, const unsigned short* __restrict__ wsW2,
    const float* __restrict__ b2, const float* __restrict__ W3,
    const float* __restrict__ b3, const float* __restrict__ state0,
    float* __restrict__ out) {
  __shared__ __align__(16) unsigned short A_lds[2 * LDA]; // h1 bf16, padded rows
  __shared__ __align__(16) float partial[2][4];           // [chain][wave]

  const int tid  = threadIdx.x;   // 0..255 == column j
  const int lane = tid & 63;
  const int wave = tid >> 6;      // 0..3
  const int j    = tid;
  const int b0   = blockIdx.x * 2;

  // --- persistent constants ---
  const float w10 = W1[j];
  const float w11 = W1[HID + j];
  const float b1j = b1[j];
  const float b3v = b3[0];
  float b2c[4], w3c[4];
#pragma unroll
  for (int t = 0; t < 4; ++t) {
    const int c = wave * 64 + t * 16 + (lane & 15);
    b2c[t] = b2[c];
    w3c[t] = W3[c];
  }

  // --- B fragments: wave owns tiles wave*4 .. wave*4+3 (64 columns) ---
  short8 bf[4][8];
  {
    const short8* wp = (const short8*)wsW2;
#pragma unroll
    for (int t = 0; t < 4; ++t)
#pragma unroll
      for (int kc = 0; kc < 8; ++kc)
        bf[t][kc] = wp[((wave * 4 + t) * 8 + kc) * 64 + lane];
  }

  // --- A-read address, unmasked (pad lanes read duplicate chain rows; only C rows 0,4
  //     consumed, each depends solely on its own lanes' A values) ---
  const int aoff = ((lane >> 2) & 1) * LDA + (lane >> 4) * 8; // ushort index

  const f32x4 kZero = {0.f, 0.f, 0.f, 0.f};

  float y0 = state0[b0];
  float y1 = state0[b0 + 1];

  const float* xp = x + b0;
  float* yo = out + b0;

  // x prefetch double buffer (8 steps ahead); xa_r = x_r*W1[0,j] + b1[j]
  float2 xb[8], xn[8];
  float xa0[8], xa1[8];
#pragma unroll
  for (int i = 0; i < 8; ++i) xb[i] = *(const float2*)&xp[i * BATCH];
#pragma unroll
  for (int i = 0; i < 8; ++i) {
    xa0[i] = xb[i].x * w10 + b1j;
    xa1[i] = xb[i].y * w10 + b1j;
  }

  // --- prologue: partials init so step-0 fold yields sum = -b3 -> pre = base, f = 0 ---
  if (tid < 8) ((float*)partial)[tid] = -0.25f * b3v;
  // base'' = xa + w11*y + w11*b3 (b3 pre-folded; fold's sum carries -b3 at step 0)
  float base0 = __builtin_fmaf(b3v, w11, __builtin_fmaf(y0, w11, xa0[0]));
  float base1 = __builtin_fmaf(b3v, w11, __builtin_fmaf(y1, w11, xa1[0]));
  __syncthreads(); // partials visible (acts as the "bar2" preceding step 0)

  for (int tb = 0; tb < SEQ; tb += 8) {
    if (tb + 8 < SEQ) {
      const float* xq = xp + (tb + 8) * BATCH;
#pragma unroll
      for (int i = 0; i < 8; ++i) xn[i] = *(const float2*)&xq[i * BATCH];
    }

    float2 yh[8]; // yh[i] = Y_{tb+i}: the state ENTERING step tb+i (fold applies f(tb+i-1))

#pragma unroll
    for (int i = 0; i < 8; ++i) {
      // --- fold partials of step t-1 (post-bar2 critical path): 3 adds + fma + tanh ---
      const f32x4 q0 = *(const f32x4*)&partial[0][0];
      const f32x4 q1 = *(const f32x4*)&partial[1][0];
      const float s0sum = (q0[0] + q0[1]) + (q0[2] + q0[3]); // = f(t-1) - b3
      const float s1sum = (q1[0] + q1[1]) + (q1[2] + q1[3]);
      const float pre0 = __builtin_fmaf(s0sum, w11, base0);  // b3 already inside base
      const float pre1 = __builtin_fmaf(s1sum, w11, base1);
      A_lds[j]       = f2bf_rne(tanh_e(pre0));
      A_lds[LDA + j] = f2bf_rne(tanh_e(pre1));
      __syncthreads(); // bar1: h1 visible

      // --- A-fragments: unconditional vector reads (pad rows -> disjoint banks) ---
      short8 areg[8];
#pragma unroll
      for (int kc = 0; kc < 8; ++kc)
        areg[kc] = *(const short8*)&A_lds[aoff + kc * 32];

      // --- tiles 0,1: K=256 over 8 chunks (2 indep acc chains) ---
      f32x4 acc0, acc1, acc2, acc3;
      {
        const bf16x8 a = __builtin_bit_cast(bf16x8, areg[0]);
        acc0 = __builtin_amdgcn_mfma_f32_16x16x32_bf16(a, __builtin_bit_cast(bf16x8, bf[0][0]), kZero, 0, 0, 0);
        acc1 = __builtin_amdgcn_mfma_f32_16x16x32_bf16(a, __builtin_bit_cast(bf16x8, bf[1][0]), kZero, 0, 0, 0);
      }
#pragma unroll
      for (int kc = 1; kc < 8; ++kc) {
        const bf16x8 a = __builtin_bit_cast(bf16x8, areg[kc]);
        acc0 = __builtin_amdgcn_mfma_f32_16x16x32_bf16(a, __builtin_bit_cast(bf16x8, bf[0][kc]), acc0, 0, 0, 0);
        acc1 = __builtin_amdgcn_mfma_f32_16x16x32_bf16(a, __builtin_bit_cast(bf16x8, bf[1][kc]), acc1, 0, 0, 0);
      }

      // --- off-path work in the MFMA shadow: y update (-> Y_{tb+i}), history, next base ---
      y0 += s0sum + b3v; // DT = 1.0; y now = state entering step tb+i
      y1 += s1sum + b3v;
      yh[i] = float2{y0, y1};
      {
        const float xaN0 = (i < 7) ? xa0[i + 1] : xn[0].x * w10 + b1j;
        const float xaN1 = (i < 7) ? xa1[i + 1] : xn[0].y * w10 + b1j;
        base0 = __builtin_fmaf(b3v, w11, __builtin_fmaf(y0, w11, xaN0));
        base1 = __builtin_fmaf(b3v, w11, __builtin_fmaf(y1, w11, xaN1));
      }

      // --- s01 + its DPP reduce (hides under tiles-2,3 MFMA block) ---
      const float s01 = tanh_e(acc0[0] + b2c[0]) * w3c[0] +
                        tanh_e(acc1[0] + b2c[1]) * w3c[1];
      const float r01 = row16_sum_to_lane15(s01);

      // --- tiles 2,3 ---
      {
        const bf16x8 a = __builtin_bit_cast(bf16x8, areg[0]);
        acc2 = __builtin_amdgcn_mfma_f32_16x16x32_bf16(a, __builtin_bit_cast(bf16x8, bf[2][0]), kZero, 0, 0, 0);
        acc3 = __builtin_amdgcn_mfma_f32_16x16x32_bf16(a, __builtin_bit_cast(bf16x8, bf[3][0]), kZero, 0, 0, 0);
      }
#pragma unroll
      for (int kc = 1; kc < 8; ++kc) {
        const bf16x8 a = __builtin_bit_cast(bf16x8, areg[kc]);
        acc2 = __builtin_amdgcn_mfma_f32_16x16x32_bf16(a, __builtin_bit_cast(bf16x8, bf[2][kc]), acc2, 0, 0, 0);
        acc3 = __builtin_amdgcn_mfma_f32_16x16x32_bf16(a, __builtin_bit_cast(bf16x8, bf[3][kc]), acc3, 0, 0, 0);
      }

      const float s23 = tanh_e(acc2[0] + b2c[2]) * w3c[2] +
                        tanh_e(acc3[0] + b2c[3]) * w3c[3];
      const float r = row16_sum_to_lane15(s23) + r01;

      if ((lane & 15) == 15 && lane < 32)
        partial[lane >> 4][wave] = r;
      __syncthreads(); // bar2: partials visible (folded at top of next step)
    }

    // --- burst-store this block's outputs (ONE vmcnt drain per 8 steps, wave 0 only) ---
    if (tid == 0) {
#pragma unroll
      for (int i = 0; i < 8; ++i)
        *(float2*)&yo[(tb + i) * BATCH] = yh[i]; // out[t] = Y_t (pre-update state)
    }

    if (tb + 8 < SEQ) {
#pragma unroll
      for (int i = 0; i < 8; ++i) xb[i] = xn[i];
#pragma unroll
      for (int i = 0; i < 8; ++i) {
        xa0[i] = xb[i].x * w10 + b1j;
        xa1[i] = xb[i].y * w10 + b1j;
      }
    }
  }
}

extern "C" void kernel_launch(void* const* d_in, const int* in_sizes, int n_in,
                              void* d_out, int out_size, void* d_ws, size_t ws_size,
                              hipStream_t stream) {
  const float* x  = (const float*)d_in[0];
  const float* W1 = (const float*)d_in[1];
  const float* b1 = (const float*)d_in[2];
  const float* W2 = (const float*)d_in[3];
  const float* b2 = (const float*)d_in[4];
  const float* W3 = (const float*)d_in[5];
  const float* b3 = (const float*)d_in[6];
  const float* s0 = (const float*)d_in[7];
  unsigned short* ws = (unsigned short*)d_ws; // 65536 bf16 = 128 KB
  float* out = (float*)d_out;

  pack_w2_kernel<<<256, 256, 0, stream>>>(W2, ws);
  odenet_kernel<<<256, 256, 0, stream>>>(x, W1, b1, ws, b2, W3, b3, s0, out);
}